// Round 7
// baseline (374.579 us; speedup 1.0000x reference)
//
#include <hip/hip_runtime.h>
#include <hip/hip_fp16.h>
#include <cstdint>
#include <cstddef>

#define NN 1024   // nodes
#define BB 32     // batch

typedef _Float16 f16x8 __attribute__((ext_vector_type(8)));
typedef _Float16 f16x4 __attribute__((ext_vector_type(4)));
typedef float f32x4 __attribute__((ext_vector_type(4)));
typedef float f32x16 __attribute__((ext_vector_type(16)));

__device__ __forceinline__ void load_lds16(const void* g, void* l) {
  __builtin_amdgcn_global_load_lds(
      (const __attribute__((address_space(1))) void*)g,
      (__attribute__((address_space(3))) void*)l, 16, 0, 0);
}

// ---------------------------------------------------------------------------
// K0: build the 10 support matrices (shared by both gconvs), fp16.
// ---------------------------------------------------------------------------
__global__ __launch_bounds__(256) void k_build_amats(
    const float* __restrict__ adj, const float* __restrict__ mask,
    _Float16* __restrict__ A) {
  int q = blockIdx.x * 256 + threadIdx.x;  // 0..262143 quads
  int i = q >> 8;
  int j0 = (q & 255) << 2;
  size_t off = (size_t)i * 1024 + j0;
  float4 a0 = *(const float4*)(adj + off);
  float4 a1 = *(const float4*)(adj + (1u << 20) + off);
  f16x4 r;
  r[0] = a0.x; r[1] = a0.y; r[2] = a0.z; r[3] = a0.w;
  *(f16x4*)(A + off) = r;
  r[0] = a1.x; r[1] = a1.y; r[2] = a1.z; r[3] = a1.w;
  *(f16x4*)(A + (size_t)9 * 1048576 + off) = r;
#pragma unroll
  for (int l = 0; l < 8; ++l) {
    float4 mk = *(const float4*)(mask + (size_t)l * 1048576 + off);
    float4 base = (l < 4) ? a0 : a1;
    r[0] = mk.x * base.x; r[1] = mk.y * base.y;
    r[2] = mk.z * base.z; r[3] = mk.w * base.w;
    *(f16x4*)(A + (size_t)(l + 1) * 1048576 + off) = r;
  }
}

// ---------------------------------------------------------------------------
// K0b: transpose+convert Wout matrices to fp16 hi/lo [O][K]
// ---------------------------------------------------------------------------
__global__ __launch_bounds__(256) void k_prep_wout(
    const float* __restrict__ Wru, const float* __restrict__ Wc,
    _Float16* __restrict__ WThru, _Float16* __restrict__ WTlru,
    _Float16* __restrict__ WThc, _Float16* __restrict__ WTlc) {
  int id = blockIdx.x * 256 + threadIdx.x;
  if (id < 128 * 384) {
    int o = id & 127, k = id >> 7;
    float w = Wru[k * 128 + o];
    _Float16 h = (_Float16)w;
    WThru[o * 384 + k] = h;
    WTlru[o * 384 + k] = (_Float16)(w - (float)h);
  } else {
    int id2 = id - 128 * 384;
    if (id2 < 64 * 192) {
      int o = id2 & 63, k = id2 >> 6;
      float w = Wc[k * 64 + o];
      _Float16 h = (_Float16)w;
      WThc[o * 192 + k] = h;
      WTlc[o * 192 + k] = (_Float16)(w - (float)h);
    }
  }
}

// ---------------------------------------------------------------------------
// K1: build X0P fp16 [(b*1024+j)][96]: f<2 inputs, f-2<64 state, pad 0.
// ---------------------------------------------------------------------------
__global__ __launch_bounds__(256) void k_build_x0p(
    const float* __restrict__ inp, const float* __restrict__ state,
    _Float16* __restrict__ X0P) {
  const int b = blockIdx.x;        // 0..31
  const int j0 = blockIdx.y * 64;  // 0..960
  const int tid = threadIdx.x;
  for (int p = tid; p < 4096; p += 256) {
    int jj = p >> 6, f = p & 63;
    X0P[((size_t)(b * 1024 + j0 + jj)) * 96 + 2 + f] =
        (_Float16)state[(size_t)b * 65536 + (j0 + jj) * 64 + f];
  }
  if (tid < 128) {
    int jj = tid >> 1, f = tid & 1;
    X0P[((size_t)(b * 1024 + j0 + jj)) * 96 + f] =
        (_Float16)inp[(size_t)b * 2048 + (j0 + jj) * 2 + f];
    X0P[((size_t)(b * 1024 + j0 + 32 + jj)) * 96 + f] =
        (_Float16)inp[(size_t)b * 2048 + (j0 + 32 + jj) * 2 + f];
  }
  for (int p = tid; p < 64 * 32; p += 256) {
    int jj = p >> 5, f = 66 + (p & 31);
    if (f < 96)
      X0P[((size_t)(b * 1024 + j0 + jj)) * 96 + f] = (_Float16)0.f;
  }
}

// ---------------------------------------------------------------------------
// K2: proj0 GEMM via MFMA.  XP0[(j,b)][o] = sum_f x[b,j,f] * W[f,o]
// ---------------------------------------------------------------------------
template <int O>
__global__ __launch_bounds__(256, 2) void k_proj0_mfma(
    const _Float16* __restrict__ X0P, const float* __restrict__ W,
    _Float16* __restrict__ XP0, _Float16* __restrict__ XP0T) {
  constexpr int WR = O / 64;      // 2 for O=128, 1 for O=64
  constexpr int WC = 4 / WR;      // 2 or 4
  constexpr int TN = WC * 64;     // 128 or 256
  constexpr int NPT = TN / 64;    // staging chunks per thread (2 or 4)
  __shared__ _Float16 ldsB[2][TN * 32];
  const int tid = threadIdx.x;
  const int c0 = blockIdx.x * TN;  // global col base (b*1024+j), within one b
  const int b = c0 >> 10;
  const int l = tid & 63;
  const int w = tid >> 6;
  const int wr = w / WC, wc = w % WC;

  f16x8 af[4][3];
#pragma unroll
  for (int i = 0; i < 4; ++i) {
    int o = wr * 64 + i * 16 + (l & 15);
#pragma unroll
    for (int ks = 0; ks < 3; ++ks) {
#pragma unroll
      for (int e = 0; e < 8; ++e) {
        int f = ks * 32 + (l >> 4) * 8 + e;
        af[i][ks][e] = (f < 66) ? (_Float16)W[f * O + o] : (_Float16)0.f;
      }
    }
  }

  int tt[NPT], rr[NPT], qq[NPT];
#pragma unroll
  for (int u = 0; u < NPT; ++u) {
    tt[u] = u * 256 + tid;
    rr[u] = tt[u] >> 2;
    qq[u] = (tt[u] & 3) ^ (rr[u] & 3);
  }

  const int ps = ((l >> 4) ^ (l & 3)) * 8;
  int offB[4];
#pragma unroll
  for (int j = 0; j < 4; ++j)
    offB[j] = (wc * 64 + j * 16 + (l & 15)) * 32 + ps;

  f32x4 acc[4][4];
#pragma unroll
  for (int i = 0; i < 4; ++i)
#pragma unroll
    for (int j = 0; j < 4; ++j) acc[i][j] = (f32x4){0.f, 0.f, 0.f, 0.f};

#pragma unroll
  for (int u = 0; u < NPT; ++u)
    load_lds16(X0P + (size_t)(c0 + rr[u]) * 96 + qq[u] * 8,
               &ldsB[0][0] + tt[u] * 8);

  int buf = 0;
  for (int kt = 0; kt < 3; ++kt) {
    __syncthreads();
    if (kt + 1 < 3) {
#pragma unroll
      for (int u = 0; u < NPT; ++u)
        load_lds16(X0P + (size_t)(c0 + rr[u]) * 96 + (kt + 1) * 32 + qq[u] * 8,
                   &ldsB[buf ^ 1][0] + tt[u] * 8);
    }
    f16x8 bf[4];
#pragma unroll
    for (int j = 0; j < 4; ++j) bf[j] = *(const f16x8*)(&ldsB[buf][offB[j]]);
#pragma unroll
    for (int i = 0; i < 4; ++i)
#pragma unroll
      for (int j = 0; j < 4; ++j)
        acc[i][j] = __builtin_amdgcn_mfma_f32_16x16x32_f16(af[i][kt], bf[j],
                                                           acc[i][j], 0, 0, 0);
    buf ^= 1;
  }

#pragma unroll
  for (int i = 0; i < 4; ++i) {
    int ob = wr * 64 + i * 16 + (l >> 4) * 4;  // 4 consecutive o
#pragma unroll
    for (int j = 0; j < 4; ++j) {
      int jn = (c0 & 1023) + wc * 64 + j * 16 + (l & 15);
      f16x4 hv;
#pragma unroll
      for (int r = 0; r < 4; ++r) {
        hv[r] = (_Float16)acc[i][j][r];
        XP0T[((size_t)b * O + ob + r) * 1024 + jn] = hv[r];
      }
      *(f16x4*)(XP0 + ((size_t)jn * 32 + b) * O + ob) = hv;
    }
  }
}

// ---------------------------------------------------------------------------
// K3: supports GEMM on projected tensor (32x32x16 MFMA + XCD swizzle).
// XPD[(m*1024+i)][c] = sum_j A_m[i][j] * XP0T[c][j],  c = b*O+o, CN=32*O.
// 128x128 tile, BK=32, 4 waves 2x2 (64x64 each via 2x2 32x32 frags).
// T1: XCD-chunked bijective block swizzle (nwg % 8 == 0).
// ---------------------------------------------------------------------------
template <int CN>
__global__ __launch_bounds__(256, 2) void k_supports2_mfma(
    const _Float16* __restrict__ A, const _Float16* __restrict__ BT,
    _Float16* __restrict__ XPD) {
  __shared__ _Float16 ldsA[2][4096];  // [buf][128 rows][32 k]
  __shared__ _Float16 ldsB[2][4096];
  const int tid = threadIdx.x;
  constexpr int GX = CN / 128;
  const int flat = blockIdx.x + GX * blockIdx.y;
  constexpr int NWG = GX * 80;
  constexpr int CPX = NWG / 8;
  const int swz = (flat & 7) * CPX + (flat >> 3);
  const int bn = swz % GX;
  const int bm = swz / GX;
  const int l = tid & 63;
  const int w = tid >> 6;
  const int wr = w >> 1, wc = w & 1;

  const int t0 = tid, t1 = 256 + tid;
  const int r0 = t0 >> 2, q0 = (t0 & 3) ^ (r0 & 3);
  const int r1 = t1 >> 2, q1 = (t1 & 3) ^ (r1 & 3);
  const _Float16* gA0 = A + ((size_t)(bm * 128 + r0)) * 1024 + q0 * 8;
  const _Float16* gA1 = A + ((size_t)(bm * 128 + r1)) * 1024 + q1 * 8;
  const _Float16* gB0 = BT + ((size_t)(bn * 128 + r0)) * 1024 + q0 * 8;
  const _Float16* gB1 = BT + ((size_t)(bn * 128 + r1)) * 1024 + q1 * 8;

  // 32x32 fragment ds_read offsets (halfs), same slot^(row&3) swizzle
  int offA[2][2], offB[2][2];
#pragma unroll
  for (int fi = 0; fi < 2; ++fi)
#pragma unroll
    for (int ks = 0; ks < 2; ++ks) {
      int slot = ((ks * 2 + (l >> 5)) ^ (l & 3)) * 8;
      offA[fi][ks] = (wr * 64 + fi * 32 + (l & 31)) * 32 + slot;
      offB[fi][ks] = (wc * 64 + fi * 32 + (l & 31)) * 32 + slot;
    }

  f32x16 acc[2][2];
#pragma unroll
  for (int i = 0; i < 2; ++i)
#pragma unroll
    for (int j = 0; j < 2; ++j)
#pragma unroll
      for (int e = 0; e < 16; ++e) acc[i][j][e] = 0.f;

  load_lds16(gA0, &ldsA[0][0] + t0 * 8);
  load_lds16(gA1, &ldsA[0][0] + t1 * 8);
  load_lds16(gB0, &ldsB[0][0] + t0 * 8);
  load_lds16(gB1, &ldsB[0][0] + t1 * 8);

  int buf = 0;
  for (int kt = 0; kt < 32; ++kt) {
    __syncthreads();
    if (kt + 1 < 32) {
      int k0 = (kt + 1) * 32;
      load_lds16(gA0 + k0, &ldsA[buf ^ 1][0] + t0 * 8);
      load_lds16(gA1 + k0, &ldsA[buf ^ 1][0] + t1 * 8);
      load_lds16(gB0 + k0, &ldsB[buf ^ 1][0] + t0 * 8);
      load_lds16(gB1 + k0, &ldsB[buf ^ 1][0] + t1 * 8);
    }
    f16x8 af[2][2], bf[2][2];
#pragma unroll
    for (int fi = 0; fi < 2; ++fi)
#pragma unroll
      for (int ks = 0; ks < 2; ++ks) {
        af[fi][ks] = *(const f16x8*)(&ldsA[buf][offA[fi][ks]]);
        bf[fi][ks] = *(const f16x8*)(&ldsB[buf][offB[fi][ks]]);
      }
#pragma unroll
    for (int fi = 0; fi < 2; ++fi)
#pragma unroll
      for (int fj = 0; fj < 2; ++fj)
#pragma unroll
        for (int ks = 0; ks < 2; ++ks)
          acc[fi][fj] = __builtin_amdgcn_mfma_f32_32x32x16_f16(
              af[fi][ks], bf[fj][ks], acc[fi][fj], 0, 0, 0);
    buf ^= 1;
  }

  // C/D layout (verified): col = lane&31, row = (e&3) + 8*(e>>2) + 4*(lane>>5)
#pragma unroll
  for (int fi = 0; fi < 2; ++fi)
#pragma unroll
    for (int fj = 0; fj < 2; ++fj) {
      int colg = bn * 128 + wc * 64 + fj * 32 + (l & 31);
      int Rb = bm * 128 + wr * 64 + fi * 32 + 4 * (l >> 5);
#pragma unroll
      for (int e = 0; e < 16; ++e) {
        int R = Rb + (e & 3) + 8 * (e >> 2);
        XPD[(size_t)R * CN + colg] = (_Float16)acc[fi][fj][e];
      }
    }
}

// ---------------------------------------------------------------------------
// K4: attention via MFMA (reads XPD rows [(s'*1024+n)][CN], s'=g*5+si).
// Writes xi/xs as fp16 hi+lo into CAT2h/CAT2l [(n*32+b)][2*O].
// ---------------------------------------------------------------------------
template <int O>
__global__ __launch_bounds__(256) void k_attend_mfma(
    const __half* __restrict__ XPD, const float* __restrict__ Watt,
    const float* __restrict__ Watt1, _Float16* __restrict__ CAT2h,
    _Float16* __restrict__ CAT2l) {
  constexpr int MTW = O / 64;       // q-tiles per wave (2 or 1)
  constexpr int KS = O / 32;        // k-steps (4 or 2)
  constexpr int SLOTS = O / 8;      // 16B slots per row (16 or 8)
  constexpr int SWZ = SLOTS - 1;
  constexpr int OH = O / 2;         // u32 per (b) slice
  const int n = blockIdx.x;
  const int tid = threadIdx.x;
  const int l = tid & 63;
  const int w = tid >> 6;

  __shared__ _Float16 xpL[160 * O];
  __shared__ float sPartL[4][160];
  __shared__ float aL[32][5];

  const int qbase = w * (O / 4);
  f16x8 afr[MTW][KS];
#pragma unroll
  for (int mt = 0; mt < MTW; ++mt) {
    const int q = qbase + mt * 16 + (l & 15);
#pragma unroll
    for (int ks = 0; ks < KS; ++ks) {
#pragma unroll
      for (int e = 0; e < 8; ++e) {
        int o = ks * 32 + (l >> 4) * 8 + e;
        afr[mt][ks][e] = (_Float16)Watt[((size_t)n * O + o) * O + q];
      }
    }
  }
  float wt1[MTW][4];
#pragma unroll
  for (int mt = 0; mt < MTW; ++mt)
#pragma unroll
    for (int r = 0; r < 4; ++r)
      wt1[mt][r] = Watt1[(size_t)n * O + qbase + mt * 16 + (l >> 4) * 4 + r];

  for (int g = 0; g < 2; ++g) {
    if (g) __syncthreads();
    {
      const uint32_t* xsrc = reinterpret_cast<const uint32_t*>(XPD);
      uint32_t* xdst = reinterpret_cast<uint32_t*>(xpL);
      for (int p = tid; p < 160 * OH; p += 256) {
        int row = p / OH;
        int oh = p - row * OH;
        int slot = oh >> 2;
        int phys = slot ^ (row & SWZ);
        int si = row >> 5, b = row & 31;
        size_t gi = ((size_t)(g * 5 + si) * 1024 + n) * (size_t)(16 * O) +
                    b * OH + oh;
        xdst[row * OH + phys * 4 + (oh & 3)] = xsrc[gi];
      }
    }
    __syncthreads();

    for (int nt = 0; nt < 10; ++nt) {
      f32x4 acc[MTW];
#pragma unroll
      for (int mt = 0; mt < MTW; ++mt) acc[mt] = (f32x4){0.f, 0.f, 0.f, 0.f};
      const int row = nt * 16 + (l & 15);
#pragma unroll
      for (int ks = 0; ks < KS; ++ks) {
        int phys = (ks * 4 + (l >> 4)) ^ (row & SWZ);
        f16x8 bf = *(const f16x8*)(&xpL[row * O + phys * 8]);
#pragma unroll
        for (int mt = 0; mt < MTW; ++mt)
          acc[mt] = __builtin_amdgcn_mfma_f32_16x16x32_f16(afr[mt][ks], bf,
                                                           acc[mt], 0, 0, 0);
      }
      float sp = 0.f;
#pragma unroll
      for (int mt = 0; mt < MTW; ++mt)
#pragma unroll
        for (int r = 0; r < 4; ++r)
          sp += fmaxf(acc[mt][r], 0.f) * wt1[mt][r];
      sp += __shfl_xor(sp, 16);
      sp += __shfl_xor(sp, 32);
      if (l < 16) sPartL[w][nt * 16 + l] = sp;
    }
    __syncthreads();

    if (tid < 32) {
      const int b = tid;
      float sv[5];
#pragma unroll
      for (int k = 0; k < 5; ++k) {
        int row = k * 32 + b;
        sv[k] = sPartL[0][row] + sPartL[1][row] + sPartL[2][row] +
                sPartL[3][row];
      }
      float mx = sv[0];
#pragma unroll
      for (int k = 1; k < 5; ++k) mx = fmaxf(mx, sv[k]);
      float e[5], sum = 0.f;
#pragma unroll
      for (int k = 0; k < 5; ++k) {
        e[k] = expf(sv[k] - mx);
        sum += e[k];
      }
      float inv = 1.f / sum;
#pragma unroll
      for (int k = 0; k < 5; ++k) aL[b][k] = e[k] * inv;
    }
    __syncthreads();

    for (int it = 0; it < SLOTS * 32 / 256; ++it) {
      int idx = it * 256 + tid;
      int b = idx & 31;
      int sc = idx >> 5;
      float o8[8] = {0.f, 0.f, 0.f, 0.f, 0.f, 0.f, 0.f, 0.f};
#pragma unroll
      for (int si = 0; si < 5; ++si) {
        int row = si * 32 + b;
        int phys = sc ^ (row & SWZ);
        f16x8 xv = *(const f16x8*)(&xpL[row * O + phys * 8]);
        float a = aL[b][si];
#pragma unroll
        for (int j = 0; j < 8; ++j) o8[j] += a * (float)xv[j];
      }
      f16x8 hv, lv;
#pragma unroll
      for (int j = 0; j < 8; ++j) {
        hv[j] = (_Float16)o8[j];
        lv[j] = (_Float16)(o8[j] - (float)hv[j]);
      }
      size_t doff = ((size_t)n * 32 + b) * (2 * O) + g * O + sc * 8;
      *reinterpret_cast<f16x8*>(CAT2h + doff) = hv;
      *reinterpret_cast<f16x8*>(CAT2l + doff) = lv;
    }
  }
}

// ---------------------------------------------------------------------------
// K5: ru Wout GEMM via split-fp16 MFMA + fused sigmoid.
// ---------------------------------------------------------------------------
__global__ __launch_bounds__(256, 2) void k_wout_ru_mfma(
    const _Float16* __restrict__ CAT2h, const _Float16* __restrict__ CAT2l,
    const _Float16* __restrict__ XP0, const _Float16* __restrict__ WTh,
    const _Float16* __restrict__ WTl, const float* __restrict__ bias,
    const float* __restrict__ hx, float* __restrict__ RHX,
    float* __restrict__ UBUF) {
  constexpr int KTOT = 384, KC = 8, KT = 12;
  __shared__ _Float16 ldsAh[2][4096];
  __shared__ _Float16 ldsAl[2][4096];
  __shared__ _Float16 ldsBh[2][4096];
  __shared__ _Float16 ldsBl[2][4096];
  const int tid = threadIdx.x;
  const int blk = blockIdx.x;
  const int l = tid & 63;
  const int w = tid >> 6;
  const int wr = w >> 1, wc = w & 1;

  const int t0 = tid, t1 = 256 + tid;
  const int r0 = t0 >> 2, q0 = (t0 & 3) ^ (r0 & 3);
  const int r1 = t1 >> 2, q1 = (t1 & 3) ^ (r1 & 3);
  const size_t R0 = (size_t)blk * 128 + r0, R1 = (size_t)blk * 128 + r1;
  const _Float16* pA0ch = CAT2h + R0 * 256 + q0 * 8;
  const _Float16* pA1ch = CAT2h + R1 * 256 + q1 * 8;
  const _Float16* pA0cl = CAT2l + R0 * 256 + q0 * 8;
  const _Float16* pA1cl = CAT2l + R1 * 256 + q1 * 8;
  const _Float16* pA0x = XP0 + R0 * 128 + q0 * 8;
  const _Float16* pA1x = XP0 + R1 * 128 + q1 * 8;
  const _Float16* pB0h = WTh + (size_t)r0 * KTOT + q0 * 8;
  const _Float16* pB1h = WTh + (size_t)r1 * KTOT + q1 * 8;
  const _Float16* pB0l = WTl + (size_t)r0 * KTOT + q0 * 8;
  const _Float16* pB1l = WTl + (size_t)r1 * KTOT + q1 * 8;

  const int ps = ((l >> 4) ^ (l & 3)) * 8;
  int offA[4], offB[4];
#pragma unroll
  for (int i = 0; i < 4; ++i) {
    offA[i] = (wr * 64 + i * 16 + (l & 15)) * 32 + ps;
    offB[i] = (wc * 64 + i * 16 + (l & 15)) * 32 + ps;
  }

  f32x4 acc[4][4];
#pragma unroll
  for (int i = 0; i < 4; ++i)
#pragma unroll
    for (int j = 0; j < 4; ++j) acc[i][j] = (f32x4){0.f, 0.f, 0.f, 0.f};

  load_lds16(pA0ch, &ldsAh[0][0] + t0 * 8);
  load_lds16(pA1ch, &ldsAh[0][0] + t1 * 8);
  load_lds16(pA0cl, &ldsAl[0][0] + t0 * 8);
  load_lds16(pA1cl, &ldsAl[0][0] + t1 * 8);
  load_lds16(pB0h, &ldsBh[0][0] + t0 * 8);
  load_lds16(pB1h, &ldsBh[0][0] + t1 * 8);
  load_lds16(pB0l, &ldsBl[0][0] + t0 * 8);
  load_lds16(pB1l, &ldsBl[0][0] + t1 * 8);

  int buf = 0;
  for (int kt = 0; kt < KT; ++kt) {
    __syncthreads();
    if (kt + 1 < KT) {
      int k1 = kt + 1;
      const _Float16* a0 =
          (k1 < KC) ? pA0ch + k1 * 32 : pA0x + (k1 - KC) * 32;
      const _Float16* a1 =
          (k1 < KC) ? pA1ch + k1 * 32 : pA1x + (k1 - KC) * 32;
      load_lds16(a0, &ldsAh[buf ^ 1][0] + t0 * 8);
      load_lds16(a1, &ldsAh[buf ^ 1][0] + t1 * 8);
      if (k1 < KC) {
        load_lds16(pA0cl + k1 * 32, &ldsAl[buf ^ 1][0] + t0 * 8);
        load_lds16(pA1cl + k1 * 32, &ldsAl[buf ^ 1][0] + t1 * 8);
      }
      load_lds16(pB0h + k1 * 32, &ldsBh[buf ^ 1][0] + t0 * 8);
      load_lds16(pB1h + k1 * 32, &ldsBh[buf ^ 1][0] + t1 * 8);
      load_lds16(pB0l + k1 * 32, &ldsBl[buf ^ 1][0] + t0 * 8);
      load_lds16(pB1l + k1 * 32, &ldsBl[buf ^ 1][0] + t1 * 8);
    }
    f16x8 ah[4], bh[4], bl[4];
#pragma unroll
    for (int i = 0; i < 4; ++i) ah[i] = *(const f16x8*)(&ldsAh[buf][offA[i]]);
#pragma unroll
    for (int i = 0; i < 4; ++i) bh[i] = *(const f16x8*)(&ldsBh[buf][offB[i]]);
#pragma unroll
    for (int i = 0; i < 4; ++i) bl[i] = *(const f16x8*)(&ldsBl[buf][offB[i]]);
#pragma unroll
    for (int i = 0; i < 4; ++i)
#pragma unroll
      for (int j = 0; j < 4; ++j) {
        acc[i][j] = __builtin_amdgcn_mfma_f32_16x16x32_f16(ah[i], bh[j],
                                                           acc[i][j], 0, 0, 0);
        acc[i][j] = __builtin_amdgcn_mfma_f32_16x16x32_f16(ah[i], bl[j],
                                                           acc[i][j], 0, 0, 0);
      }
    if (kt < KC) {
      f16x8 al[4];
#pragma unroll
      for (int i = 0; i < 4; ++i)
        al[i] = *(const f16x8*)(&ldsAl[buf][offA[i]]);
#pragma unroll
      for (int i = 0; i < 4; ++i)
#pragma unroll
        for (int j = 0; j < 4; ++j)
          acc[i][j] = __builtin_amdgcn_mfma_f32_16x16x32_f16(al[i], bh[j],
                                                             acc[i][j], 0, 0, 0);
    }
    buf ^= 1;
  }

#pragma unroll
  for (int i = 0; i < 4; ++i) {
    int R = blk * 128 + wr * 64 + i * 16 + (l >> 4) * 4;
#pragma unroll
    for (int j = 0; j < 4; ++j) {
      int o = wc * 64 + j * 16 + (l & 15);
      float bv = bias[o];
#pragma unroll
      for (int rr = 0; rr < 4; ++rr) {
        int Rr = R + rr;
        int n = Rr >> 5, b = Rr & 31;
        size_t base = ((size_t)b * NN + n) * 64;
        float val = 1.f / (1.f + expf(-(acc[i][j][rr] + bv)));
        if (o < 64)
          RHX[base + o] = val * hx[base + o];
        else
          UBUF[base + (o - 64)] = val;
      }
    }
  }
}

// ---------------------------------------------------------------------------
// K6: candidate Wout GEMM (plain fp16 MFMA; terminal op, no amplification)
// + fused tanh + gate -> out.
// ---------------------------------------------------------------------------
__global__ __launch_bounds__(256, 2) void k_wout_c_mfma(
    const _Float16* __restrict__ CAT2h, const _Float16* __restrict__ XP0,
    const _Float16* __restrict__ WTh, const float* __restrict__ bias,
    const float* __restrict__ UBUF, const float* __restrict__ hx,
    float* __restrict__ out) {
  constexpr int KTOT = 192, KC = 4, KT = 6;
  __shared__ _Float16 ldsAh[2][4096];
  __shared__ _Float16 ldsBh[2][2048];
  const int tid = threadIdx.x;
  const int blk = blockIdx.x;
  const int l = tid & 63;
  const int w = tid >> 6;

  const int t0 = tid, t1 = 256 + tid;
  const int r0 = t0 >> 2, q0 = (t0 & 3) ^ (r0 & 3);
  const int r1 = t1 >> 2, q1 = (t1 & 3) ^ (r1 & 3);
  const size_t R0 = (size_t)blk * 128 + r0, R1 = (size_t)blk * 128 + r1;
  const _Float16* pA0ch = CAT2h + R0 * 128 + q0 * 8;
  const _Float16* pA1ch = CAT2h + R1 * 128 + q1 * 8;
  const _Float16* pA0x = XP0 + R0 * 64 + q0 * 8;
  const _Float16* pA1x = XP0 + R1 * 64 + q1 * 8;
  const int rb = tid >> 2, qb = (tid & 3) ^ (rb & 3);
  const _Float16* pBh = WTh + (size_t)rb * KTOT + qb * 8;

  const int ps = ((l >> 4) ^ (l & 3)) * 8;
  int offA[2], offB[4];
#pragma unroll
  for (int i = 0; i < 2; ++i)
    offA[i] = (w * 32 + i * 16 + (l & 15)) * 32 + ps;
#pragma unroll
  for (int j = 0; j < 4; ++j) offB[j] = (j * 16 + (l & 15)) * 32 + ps;

  f32x4 acc[2][4];
#pragma unroll
  for (int i = 0; i < 2; ++i)
#pragma unroll
    for (int j = 0; j < 4; ++j) acc[i][j] = (f32x4){0.f, 0.f, 0.f, 0.f};

  load_lds16(pA0ch, &ldsAh[0][0] + t0 * 8);
  load_lds16(pA1ch, &ldsAh[0][0] + t1 * 8);
  load_lds16(pBh, &ldsBh[0][0] + tid * 8);

  int buf = 0;
  for (int kt = 0; kt < KT; ++kt) {
    __syncthreads();
    if (kt + 1 < KT) {
      int k1 = kt + 1;
      const _Float16* a0 =
          (k1 < KC) ? pA0ch + k1 * 32 : pA0x + (k1 - KC) * 32;
      const _Float16* a1 =
          (k1 < KC) ? pA1ch + k1 * 32 : pA1x + (k1 - KC) * 32;
      load_lds16(a0, &ldsAh[buf ^ 1][0] + t0 * 8);
      load_lds16(a1, &ldsAh[buf ^ 1][0] + t1 * 8);
      load_lds16(pBh + k1 * 32, &ldsBh[buf ^ 1][0] + tid * 8);
    }
    f16x8 ah[2], bh[4];
#pragma unroll
    for (int i = 0; i < 2; ++i) ah[i] = *(const f16x8*)(&ldsAh[buf][offA[i]]);
#pragma unroll
    for (int j = 0; j < 4; ++j) bh[j] = *(const f16x8*)(&ldsBh[buf][offB[j]]);
#pragma unroll
    for (int i = 0; i < 2; ++i)
#pragma unroll
      for (int j = 0; j < 4; ++j)
        acc[i][j] = __builtin_amdgcn_mfma_f32_16x16x32_f16(ah[i], bh[j],
                                                           acc[i][j], 0, 0, 0);
    buf ^= 1;
  }

#pragma unroll
  for (int i = 0; i < 2; ++i) {
    int R = blk * 128 + w * 32 + i * 16 + (l >> 4) * 4;
#pragma unroll
    for (int j = 0; j < 4; ++j) {
      int o = j * 16 + (l & 15);
      float bv = bias[o];
#pragma unroll
      for (int rr = 0; rr < 4; ++rr) {
        int Rr = R + rr;
        int n = Rr >> 5, b = Rr & 31;
        size_t idx = ((size_t)b * NN + n) * 64 + o;
        float cval = tanhf(acc[i][j][rr] + bv);
        float u = UBUF[idx];
        out[idx] = u * hx[idx] + (1.f - u) * cval;
      }
    }
  }
}

// ---------------------------------------------------------------------------
extern "C" void kernel_launch(void* const* d_in, const int* in_sizes, int n_in,
                              void* d_out, int out_size, void* d_ws,
                              size_t ws_size, hipStream_t stream) {
  const float* inputs   = (const float*)d_in[0];
  const float* hx       = (const float*)d_in[1];
  const float* adj      = (const float*)d_in[2];
  const float* mask     = (const float*)d_in[3];
  const float* W_ru     = (const float*)d_in[4];
  const float* Watt_ru  = (const float*)d_in[5];
  const float* Watt1_ru = (const float*)d_in[6];
  const float* Wout_ru  = (const float*)d_in[7];
  const float* b_ru     = (const float*)d_in[8];
  const float* W_c      = (const float*)d_in[9];
  const float* Watt_c   = (const float*)d_in[10];
  const float* Watt1_c  = (const float*)d_in[11];
  const float* Wout_c   = (const float*)d_in[12];
  const float* b_c      = (const float*)d_in[13];

  // workspace arena (~178.5 MB), same as round 6
  char* ws = (char*)d_ws;
  _Float16*  X0P   = (_Float16*)(ws);
  _Float16*  XPD   = (_Float16*)(ws + 6291456);
  _Float16*  XP0   = (_Float16*)(ws + 90177536);
  _Float16*  XP0T  = (_Float16*)(ws + 98566144);
  _Float16*  CAT2h = (_Float16*)(ws + 106954752);
  _Float16*  CAT2l = (_Float16*)(ws + 123731968);
  float*     RHX   = (float*)(ws + 140509184);
  float*     UBUF  = (float*)(ws + 148897792);
  _Float16*  A_all = (_Float16*)(ws + 157286400);
  _Float16*  WThru = (_Float16*)(ws + 178257920);
  _Float16*  WTlru = (_Float16*)(ws + 178356224);
  _Float16*  WThc  = (_Float16*)(ws + 178454528);
  _Float16*  WTlc  = (_Float16*)(ws + 178479104);
  float*     out   = (float*)d_out;

  k_build_amats<<<1024, 256, 0, stream>>>(adj, mask, A_all);
  k_prep_wout<<<240, 256, 0, stream>>>(Wout_ru, Wout_c, WThru, WTlru, WThc,
                                       WTlc);

  // ---- gate gconv (O = 2U = 128) ----
  k_build_x0p<<<dim3(32, 16), 256, 0, stream>>>(inputs, hx, X0P);
  k_proj0_mfma<128><<<256, 256, 0, stream>>>(X0P, W_ru, XP0, XP0T);
  k_supports2_mfma<4096><<<dim3(32, 80), 256, 0, stream>>>(A_all, XP0T, XPD);
  k_attend_mfma<128><<<1024, 256, 0, stream>>>((const __half*)XPD, Watt_ru,
                                               Watt1_ru, CAT2h, CAT2l);
  k_wout_ru_mfma<<<256, 256, 0, stream>>>(CAT2h, CAT2l, XP0, WThru, WTlru,
                                          b_ru, hx, RHX, UBUF);
  // ---- candidate gconv (O = U = 64), state = r*hx ----
  k_build_x0p<<<dim3(32, 16), 256, 0, stream>>>(inputs, RHX, X0P);
  k_proj0_mfma<64><<<128, 256, 0, stream>>>(X0P, W_c, XP0, XP0T);
  k_supports2_mfma<2048><<<dim3(16, 80), 256, 0, stream>>>(A_all, XP0T, XPD);
  k_attend_mfma<64><<<1024, 256, 0, stream>>>((const __half*)XPD, Watt_c,
                                              Watt1_c, CAT2h, CAT2l);
  k_wout_c_mfma<<<256, 256, 0, stream>>>(CAT2h, XP0, WThc, b_c,
                                         UBUF, hx, out);
}

// Round 8
// 341.896 us; speedup vs baseline: 1.0956x; 1.0956x over previous
//
#include <hip/hip_runtime.h>
#include <hip/hip_fp16.h>
#include <cstdint>
#include <cstddef>

#define NN 1024   // nodes
#define BB 32     // batch

typedef _Float16 f16x8 __attribute__((ext_vector_type(8)));
typedef _Float16 f16x4 __attribute__((ext_vector_type(4)));
typedef float f32x4 __attribute__((ext_vector_type(4)));

__device__ __forceinline__ void load_lds16(const void* g, void* l) {
  __builtin_amdgcn_global_load_lds(
      (const __attribute__((address_space(1))) void*)g,
      (__attribute__((address_space(3))) void*)l, 16, 0, 0);
}

// ---------------------------------------------------------------------------
// K0: build the 10 support matrices (shared by both gconvs), fp16.
// ---------------------------------------------------------------------------
__global__ __launch_bounds__(256) void k_build_amats(
    const float* __restrict__ adj, const float* __restrict__ mask,
    _Float16* __restrict__ A) {
  int q = blockIdx.x * 256 + threadIdx.x;  // 0..262143 quads
  int i = q >> 8;
  int j0 = (q & 255) << 2;
  size_t off = (size_t)i * 1024 + j0;
  float4 a0 = *(const float4*)(adj + off);
  float4 a1 = *(const float4*)(adj + (1u << 20) + off);
  f16x4 r;
  r[0] = a0.x; r[1] = a0.y; r[2] = a0.z; r[3] = a0.w;
  *(f16x4*)(A + off) = r;
  r[0] = a1.x; r[1] = a1.y; r[2] = a1.z; r[3] = a1.w;
  *(f16x4*)(A + (size_t)9 * 1048576 + off) = r;
#pragma unroll
  for (int l = 0; l < 8; ++l) {
    float4 mk = *(const float4*)(mask + (size_t)l * 1048576 + off);
    float4 base = (l < 4) ? a0 : a1;
    r[0] = mk.x * base.x; r[1] = mk.y * base.y;
    r[2] = mk.z * base.z; r[3] = mk.w * base.w;
    *(f16x4*)(A + (size_t)(l + 1) * 1048576 + off) = r;
  }
}

// ---------------------------------------------------------------------------
// K0b: transpose+convert Wout matrices to fp16 hi/lo [O][K]
// ---------------------------------------------------------------------------
__global__ __launch_bounds__(256) void k_prep_wout(
    const float* __restrict__ Wru, const float* __restrict__ Wc,
    _Float16* __restrict__ WThru, _Float16* __restrict__ WTlru,
    _Float16* __restrict__ WThc, _Float16* __restrict__ WTlc) {
  int id = blockIdx.x * 256 + threadIdx.x;
  if (id < 128 * 384) {
    int o = id & 127, k = id >> 7;
    float w = Wru[k * 128 + o];
    _Float16 h = (_Float16)w;
    WThru[o * 384 + k] = h;
    WTlru[o * 384 + k] = (_Float16)(w - (float)h);
  } else {
    int id2 = id - 128 * 384;
    if (id2 < 64 * 192) {
      int o = id2 & 63, k = id2 >> 6;
      float w = Wc[k * 64 + o];
      _Float16 h = (_Float16)w;
      WThc[o * 192 + k] = h;
      WTlc[o * 192 + k] = (_Float16)(w - (float)h);
    }
  }
}

// ---------------------------------------------------------------------------
// K1: build X0P fp16 [(b*1024+j)][96]: f<2 inputs, f-2<64 state, pad 0.
// ---------------------------------------------------------------------------
__global__ __launch_bounds__(256) void k_build_x0p(
    const float* __restrict__ inp, const float* __restrict__ state,
    _Float16* __restrict__ X0P) {
  const int b = blockIdx.x;        // 0..31
  const int j0 = blockIdx.y * 64;  // 0..960
  const int tid = threadIdx.x;
  for (int p = tid; p < 4096; p += 256) {
    int jj = p >> 6, f = p & 63;
    X0P[((size_t)(b * 1024 + j0 + jj)) * 96 + 2 + f] =
        (_Float16)state[(size_t)b * 65536 + (j0 + jj) * 64 + f];
  }
  if (tid < 128) {
    int jj = tid >> 1, f = tid & 1;
    X0P[((size_t)(b * 1024 + j0 + jj)) * 96 + f] =
        (_Float16)inp[(size_t)b * 2048 + (j0 + jj) * 2 + f];
    X0P[((size_t)(b * 1024 + j0 + 32 + jj)) * 96 + f] =
        (_Float16)inp[(size_t)b * 2048 + (j0 + 32 + jj) * 2 + f];
  }
  for (int p = tid; p < 64 * 32; p += 256) {
    int jj = p >> 5, f = 66 + (p & 31);
    if (f < 96)
      X0P[((size_t)(b * 1024 + j0 + jj)) * 96 + f] = (_Float16)0.f;
  }
}

// ---------------------------------------------------------------------------
// K2: proj0 GEMM via MFMA.  XP0[(j,b)][o] = sum_f x[b,j,f] * W[f,o]
// ---------------------------------------------------------------------------
template <int O>
__global__ __launch_bounds__(256, 2) void k_proj0_mfma(
    const _Float16* __restrict__ X0P, const float* __restrict__ W,
    _Float16* __restrict__ XP0, _Float16* __restrict__ XP0T) {
  constexpr int WR = O / 64;      // 2 for O=128, 1 for O=64
  constexpr int WC = 4 / WR;      // 2 or 4
  constexpr int TN = WC * 64;     // 128 or 256
  constexpr int NPT = TN / 64;    // staging chunks per thread (2 or 4)
  __shared__ _Float16 ldsB[2][TN * 32];
  const int tid = threadIdx.x;
  const int c0 = blockIdx.x * TN;  // global col base (b*1024+j), within one b
  const int b = c0 >> 10;
  const int l = tid & 63;
  const int w = tid >> 6;
  const int wr = w / WC, wc = w % WC;

  f16x8 af[4][3];
#pragma unroll
  for (int i = 0; i < 4; ++i) {
    int o = wr * 64 + i * 16 + (l & 15);
#pragma unroll
    for (int ks = 0; ks < 3; ++ks) {
#pragma unroll
      for (int e = 0; e < 8; ++e) {
        int f = ks * 32 + (l >> 4) * 8 + e;
        af[i][ks][e] = (f < 66) ? (_Float16)W[f * O + o] : (_Float16)0.f;
      }
    }
  }

  int tt[NPT], rr[NPT], qq[NPT];
#pragma unroll
  for (int u = 0; u < NPT; ++u) {
    tt[u] = u * 256 + tid;
    rr[u] = tt[u] >> 2;
    qq[u] = (tt[u] & 3) ^ (rr[u] & 3);
  }

  const int ps = ((l >> 4) ^ (l & 3)) * 8;
  int offB[4];
#pragma unroll
  for (int j = 0; j < 4; ++j)
    offB[j] = (wc * 64 + j * 16 + (l & 15)) * 32 + ps;

  f32x4 acc[4][4];
#pragma unroll
  for (int i = 0; i < 4; ++i)
#pragma unroll
    for (int j = 0; j < 4; ++j) acc[i][j] = (f32x4){0.f, 0.f, 0.f, 0.f};

#pragma unroll
  for (int u = 0; u < NPT; ++u)
    load_lds16(X0P + (size_t)(c0 + rr[u]) * 96 + qq[u] * 8,
               &ldsB[0][0] + tt[u] * 8);

  int buf = 0;
  for (int kt = 0; kt < 3; ++kt) {
    __syncthreads();
    if (kt + 1 < 3) {
#pragma unroll
      for (int u = 0; u < NPT; ++u)
        load_lds16(X0P + (size_t)(c0 + rr[u]) * 96 + (kt + 1) * 32 + qq[u] * 8,
                   &ldsB[buf ^ 1][0] + tt[u] * 8);
    }
    f16x8 bf[4];
#pragma unroll
    for (int j = 0; j < 4; ++j) bf[j] = *(const f16x8*)(&ldsB[buf][offB[j]]);
#pragma unroll
    for (int i = 0; i < 4; ++i)
#pragma unroll
      for (int j = 0; j < 4; ++j)
        acc[i][j] = __builtin_amdgcn_mfma_f32_16x16x32_f16(af[i][kt], bf[j],
                                                           acc[i][j], 0, 0, 0);
    buf ^= 1;
  }

#pragma unroll
  for (int i = 0; i < 4; ++i) {
    int ob = wr * 64 + i * 16 + (l >> 4) * 4;  // 4 consecutive o
#pragma unroll
    for (int j = 0; j < 4; ++j) {
      int jn = (c0 & 1023) + wc * 64 + j * 16 + (l & 15);
      f16x4 hv;
#pragma unroll
      for (int r = 0; r < 4; ++r) {
        hv[r] = (_Float16)acc[i][j][r];
        XP0T[((size_t)b * O + ob + r) * 1024 + jn] = hv[r];
      }
      *(f16x4*)(XP0 + ((size_t)jn * 32 + b) * O + ob) = hv;
    }
  }
}

// ---------------------------------------------------------------------------
// K3: supports GEMM on projected tensor (reverted to round-6 proven form:
// 16x16x32 MFMA, no block swizzle — round-7 A/B showed 32x32 frag reads
// tripled LDS bank conflicts (+34us) and XCD chunking raised FETCH).
// XPD[(m*1024+i)][c] = sum_j A_m[i][j] * XP0T[c][j],  c = b*O+o, CN=32*O.
// 128x128 tile, BK=32, 4 waves 2x2.
// ---------------------------------------------------------------------------
template <int CN>
__global__ __launch_bounds__(256, 2) void k_supports2_mfma(
    const _Float16* __restrict__ A, const _Float16* __restrict__ BT,
    _Float16* __restrict__ XPD) {
  __shared__ _Float16 ldsA[2][4096];  // [buf][128 rows][32 k]
  __shared__ _Float16 ldsB[2][4096];
  const int tid = threadIdx.x;
  const int bn = blockIdx.x;  // col tiles (CN/128)
  const int bm = blockIdx.y;  // 0..79
  const int l = tid & 63;
  const int w = tid >> 6;
  const int wr = w >> 1, wc = w & 1;

  const int t0 = tid, t1 = 256 + tid;
  const int r0 = t0 >> 2, q0 = (t0 & 3) ^ (r0 & 3);
  const int r1 = t1 >> 2, q1 = (t1 & 3) ^ (r1 & 3);
  const _Float16* gA0 = A + ((size_t)(bm * 128 + r0)) * 1024 + q0 * 8;
  const _Float16* gA1 = A + ((size_t)(bm * 128 + r1)) * 1024 + q1 * 8;
  const _Float16* gB0 = BT + ((size_t)(bn * 128 + r0)) * 1024 + q0 * 8;
  const _Float16* gB1 = BT + ((size_t)(bn * 128 + r1)) * 1024 + q1 * 8;

  const int ps = ((l >> 4) ^ (l & 3)) * 8;
  int offA[4], offB[4];
#pragma unroll
  for (int i = 0; i < 4; ++i) {
    offA[i] = (wr * 64 + i * 16 + (l & 15)) * 32 + ps;
    offB[i] = (wc * 64 + i * 16 + (l & 15)) * 32 + ps;
  }

  f32x4 acc[4][4];
#pragma unroll
  for (int i = 0; i < 4; ++i)
#pragma unroll
    for (int j = 0; j < 4; ++j) acc[i][j] = (f32x4){0.f, 0.f, 0.f, 0.f};

  load_lds16(gA0, &ldsA[0][0] + t0 * 8);
  load_lds16(gA1, &ldsA[0][0] + t1 * 8);
  load_lds16(gB0, &ldsB[0][0] + t0 * 8);
  load_lds16(gB1, &ldsB[0][0] + t1 * 8);

  int buf = 0;
  for (int kt = 0; kt < 32; ++kt) {
    __syncthreads();
    if (kt + 1 < 32) {
      int k0 = (kt + 1) * 32;
      load_lds16(gA0 + k0, &ldsA[buf ^ 1][0] + t0 * 8);
      load_lds16(gA1 + k0, &ldsA[buf ^ 1][0] + t1 * 8);
      load_lds16(gB0 + k0, &ldsB[buf ^ 1][0] + t0 * 8);
      load_lds16(gB1 + k0, &ldsB[buf ^ 1][0] + t1 * 8);
    }
    f16x8 af[4], bf[4];
#pragma unroll
    for (int i = 0; i < 4; ++i)
      af[i] = *(const f16x8*)(&ldsA[buf][offA[i]]);
#pragma unroll
    for (int i = 0; i < 4; ++i)
      bf[i] = *(const f16x8*)(&ldsB[buf][offB[i]]);
#pragma unroll
    for (int i = 0; i < 4; ++i)
#pragma unroll
      for (int j = 0; j < 4; ++j)
        acc[i][j] = __builtin_amdgcn_mfma_f32_16x16x32_f16(af[i], bf[j],
                                                           acc[i][j], 0, 0, 0);
    buf ^= 1;
  }

#pragma unroll
  for (int i = 0; i < 4; ++i) {
    int R = bm * 128 + wr * 64 + i * 16 + (l >> 4) * 4;
#pragma unroll
    for (int j = 0; j < 4; ++j) {
      int col = bn * 128 + wc * 64 + j * 16 + (l & 15);
#pragma unroll
      for (int r = 0; r < 4; ++r)
        XPD[(size_t)(R + r) * CN + col] = (_Float16)acc[i][j][r];
    }
  }
}

// ---------------------------------------------------------------------------
// K4: attention via MFMA (reads XPD rows [(s'*1024+n)][CN], s'=g*5+si).
// Writes xi/xs as fp16 hi+lo into CAT2h/CAT2l [(n*32+b)][2*O].
// ---------------------------------------------------------------------------
template <int O>
__global__ __launch_bounds__(256) void k_attend_mfma(
    const __half* __restrict__ XPD, const float* __restrict__ Watt,
    const float* __restrict__ Watt1, _Float16* __restrict__ CAT2h,
    _Float16* __restrict__ CAT2l) {
  constexpr int MTW = O / 64;       // q-tiles per wave (2 or 1)
  constexpr int KS = O / 32;        // k-steps (4 or 2)
  constexpr int SLOTS = O / 8;      // 16B slots per row (16 or 8)
  constexpr int SWZ = SLOTS - 1;
  constexpr int OH = O / 2;         // u32 per (b) slice
  const int n = blockIdx.x;
  const int tid = threadIdx.x;
  const int l = tid & 63;
  const int w = tid >> 6;

  __shared__ _Float16 xpL[160 * O];
  __shared__ float sPartL[4][160];
  __shared__ float aL[32][5];

  const int qbase = w * (O / 4);
  f16x8 afr[MTW][KS];
#pragma unroll
  for (int mt = 0; mt < MTW; ++mt) {
    const int q = qbase + mt * 16 + (l & 15);
#pragma unroll
    for (int ks = 0; ks < KS; ++ks) {
#pragma unroll
      for (int e = 0; e < 8; ++e) {
        int o = ks * 32 + (l >> 4) * 8 + e;
        afr[mt][ks][e] = (_Float16)Watt[((size_t)n * O + o) * O + q];
      }
    }
  }
  float wt1[MTW][4];
#pragma unroll
  for (int mt = 0; mt < MTW; ++mt)
#pragma unroll
    for (int r = 0; r < 4; ++r)
      wt1[mt][r] = Watt1[(size_t)n * O + qbase + mt * 16 + (l >> 4) * 4 + r];

  for (int g = 0; g < 2; ++g) {
    if (g) __syncthreads();
    {
      const uint32_t* xsrc = reinterpret_cast<const uint32_t*>(XPD);
      uint32_t* xdst = reinterpret_cast<uint32_t*>(xpL);
      for (int p = tid; p < 160 * OH; p += 256) {
        int row = p / OH;
        int oh = p - row * OH;
        int slot = oh >> 2;
        int phys = slot ^ (row & SWZ);
        int si = row >> 5, b = row & 31;
        size_t gi = ((size_t)(g * 5 + si) * 1024 + n) * (size_t)(16 * O) +
                    b * OH + oh;
        xdst[row * OH + phys * 4 + (oh & 3)] = xsrc[gi];
      }
    }
    __syncthreads();

    for (int nt = 0; nt < 10; ++nt) {
      f32x4 acc[MTW];
#pragma unroll
      for (int mt = 0; mt < MTW; ++mt) acc[mt] = (f32x4){0.f, 0.f, 0.f, 0.f};
      const int row = nt * 16 + (l & 15);
#pragma unroll
      for (int ks = 0; ks < KS; ++ks) {
        int phys = (ks * 4 + (l >> 4)) ^ (row & SWZ);
        f16x8 bf = *(const f16x8*)(&xpL[row * O + phys * 8]);
#pragma unroll
        for (int mt = 0; mt < MTW; ++mt)
          acc[mt] = __builtin_amdgcn_mfma_f32_16x16x32_f16(afr[mt][ks], bf,
                                                           acc[mt], 0, 0, 0);
      }
      float sp = 0.f;
#pragma unroll
      for (int mt = 0; mt < MTW; ++mt)
#pragma unroll
        for (int r = 0; r < 4; ++r)
          sp += fmaxf(acc[mt][r], 0.f) * wt1[mt][r];
      sp += __shfl_xor(sp, 16);
      sp += __shfl_xor(sp, 32);
      if (l < 16) sPartL[w][nt * 16 + l] = sp;
    }
    __syncthreads();

    if (tid < 32) {
      const int b = tid;
      float sv[5];
#pragma unroll
      for (int k = 0; k < 5; ++k) {
        int row = k * 32 + b;
        sv[k] = sPartL[0][row] + sPartL[1][row] + sPartL[2][row] +
                sPartL[3][row];
      }
      float mx = sv[0];
#pragma unroll
      for (int k = 1; k < 5; ++k) mx = fmaxf(mx, sv[k]);
      float e[5], sum = 0.f;
#pragma unroll
      for (int k = 0; k < 5; ++k) {
        e[k] = expf(sv[k] - mx);
        sum += e[k];
      }
      float inv = 1.f / sum;
#pragma unroll
      for (int k = 0; k < 5; ++k) aL[b][k] = e[k] * inv;
    }
    __syncthreads();

    for (int it = 0; it < SLOTS * 32 / 256; ++it) {
      int idx = it * 256 + tid;
      int b = idx & 31;
      int sc = idx >> 5;
      float o8[8] = {0.f, 0.f, 0.f, 0.f, 0.f, 0.f, 0.f, 0.f};
#pragma unroll
      for (int si = 0; si < 5; ++si) {
        int row = si * 32 + b;
        int phys = sc ^ (row & SWZ);
        f16x8 xv = *(const f16x8*)(&xpL[row * O + phys * 8]);
        float a = aL[b][si];
#pragma unroll
        for (int j = 0; j < 8; ++j) o8[j] += a * (float)xv[j];
      }
      f16x8 hv, lv;
#pragma unroll
      for (int j = 0; j < 8; ++j) {
        hv[j] = (_Float16)o8[j];
        lv[j] = (_Float16)(o8[j] - (float)hv[j]);
      }
      size_t doff = ((size_t)n * 32 + b) * (2 * O) + g * O + sc * 8;
      *reinterpret_cast<f16x8*>(CAT2h + doff) = hv;
      *reinterpret_cast<f16x8*>(CAT2l + doff) = lv;
    }
  }
}

// ---------------------------------------------------------------------------
// K5: ru Wout GEMM via split-fp16 MFMA + fused sigmoid.
// ---------------------------------------------------------------------------
__global__ __launch_bounds__(256, 2) void k_wout_ru_mfma(
    const _Float16* __restrict__ CAT2h, const _Float16* __restrict__ CAT2l,
    const _Float16* __restrict__ XP0, const _Float16* __restrict__ WTh,
    const _Float16* __restrict__ WTl, const float* __restrict__ bias,
    const float* __restrict__ hx, float* __restrict__ RHX,
    float* __restrict__ UBUF) {
  constexpr int KTOT = 384, KC = 8, KT = 12;
  __shared__ _Float16 ldsAh[2][4096];
  __shared__ _Float16 ldsAl[2][4096];
  __shared__ _Float16 ldsBh[2][4096];
  __shared__ _Float16 ldsBl[2][4096];
  const int tid = threadIdx.x;
  const int blk = blockIdx.x;
  const int l = tid & 63;
  const int w = tid >> 6;
  const int wr = w >> 1, wc = w & 1;

  const int t0 = tid, t1 = 256 + tid;
  const int r0 = t0 >> 2, q0 = (t0 & 3) ^ (r0 & 3);
  const int r1 = t1 >> 2, q1 = (t1 & 3) ^ (r1 & 3);
  const size_t R0 = (size_t)blk * 128 + r0, R1 = (size_t)blk * 128 + r1;
  const _Float16* pA0ch = CAT2h + R0 * 256 + q0 * 8;
  const _Float16* pA1ch = CAT2h + R1 * 256 + q1 * 8;
  const _Float16* pA0cl = CAT2l + R0 * 256 + q0 * 8;
  const _Float16* pA1cl = CAT2l + R1 * 256 + q1 * 8;
  const _Float16* pA0x = XP0 + R0 * 128 + q0 * 8;
  const _Float16* pA1x = XP0 + R1 * 128 + q1 * 8;
  const _Float16* pB0h = WTh + (size_t)r0 * KTOT + q0 * 8;
  const _Float16* pB1h = WTh + (size_t)r1 * KTOT + q1 * 8;
  const _Float16* pB0l = WTl + (size_t)r0 * KTOT + q0 * 8;
  const _Float16* pB1l = WTl + (size_t)r1 * KTOT + q1 * 8;

  const int ps = ((l >> 4) ^ (l & 3)) * 8;
  int offA[4], offB[4];
#pragma unroll
  for (int i = 0; i < 4; ++i) {
    offA[i] = (wr * 64 + i * 16 + (l & 15)) * 32 + ps;
    offB[i] = (wc * 64 + i * 16 + (l & 15)) * 32 + ps;
  }

  f32x4 acc[4][4];
#pragma unroll
  for (int i = 0; i < 4; ++i)
#pragma unroll
    for (int j = 0; j < 4; ++j) acc[i][j] = (f32x4){0.f, 0.f, 0.f, 0.f};

  load_lds16(pA0ch, &ldsAh[0][0] + t0 * 8);
  load_lds16(pA1ch, &ldsAh[0][0] + t1 * 8);
  load_lds16(pA0cl, &ldsAl[0][0] + t0 * 8);
  load_lds16(pA1cl, &ldsAl[0][0] + t1 * 8);
  load_lds16(pB0h, &ldsBh[0][0] + t0 * 8);
  load_lds16(pB1h, &ldsBh[0][0] + t1 * 8);
  load_lds16(pB0l, &ldsBl[0][0] + t0 * 8);
  load_lds16(pB1l, &ldsBl[0][0] + t1 * 8);

  int buf = 0;
  for (int kt = 0; kt < KT; ++kt) {
    __syncthreads();
    if (kt + 1 < KT) {
      int k1 = kt + 1;
      const _Float16* a0 =
          (k1 < KC) ? pA0ch + k1 * 32 : pA0x + (k1 - KC) * 32;
      const _Float16* a1 =
          (k1 < KC) ? pA1ch + k1 * 32 : pA1x + (k1 - KC) * 32;
      load_lds16(a0, &ldsAh[buf ^ 1][0] + t0 * 8);
      load_lds16(a1, &ldsAh[buf ^ 1][0] + t1 * 8);
      if (k1 < KC) {
        load_lds16(pA0cl + k1 * 32, &ldsAl[buf ^ 1][0] + t0 * 8);
        load_lds16(pA1cl + k1 * 32, &ldsAl[buf ^ 1][0] + t1 * 8);
      }
      load_lds16(pB0h + k1 * 32, &ldsBh[buf ^ 1][0] + t0 * 8);
      load_lds16(pB1h + k1 * 32, &ldsBh[buf ^ 1][0] + t1 * 8);
      load_lds16(pB0l + k1 * 32, &ldsBl[buf ^ 1][0] + t0 * 8);
      load_lds16(pB1l + k1 * 32, &ldsBl[buf ^ 1][0] + t1 * 8);
    }
    f16x8 ah[4], bh[4], bl[4];
#pragma unroll
    for (int i = 0; i < 4; ++i) ah[i] = *(const f16x8*)(&ldsAh[buf][offA[i]]);
#pragma unroll
    for (int i = 0; i < 4; ++i) bh[i] = *(const f16x8*)(&ldsBh[buf][offB[i]]);
#pragma unroll
    for (int i = 0; i < 4; ++i) bl[i] = *(const f16x8*)(&ldsBl[buf][offB[i]]);
#pragma unroll
    for (int i = 0; i < 4; ++i)
#pragma unroll
      for (int j = 0; j < 4; ++j) {
        acc[i][j] = __builtin_amdgcn_mfma_f32_16x16x32_f16(ah[i], bh[j],
                                                           acc[i][j], 0, 0, 0);
        acc[i][j] = __builtin_amdgcn_mfma_f32_16x16x32_f16(ah[i], bl[j],
                                                           acc[i][j], 0, 0, 0);
      }
    if (kt < KC) {
      f16x8 al[4];
#pragma unroll
      for (int i = 0; i < 4; ++i)
        al[i] = *(const f16x8*)(&ldsAl[buf][offA[i]]);
#pragma unroll
      for (int i = 0; i < 4; ++i)
#pragma unroll
        for (int j = 0; j < 4; ++j)
          acc[i][j] = __builtin_amdgcn_mfma_f32_16x16x32_f16(al[i], bh[j],
                                                             acc[i][j], 0, 0, 0);
    }
    buf ^= 1;
  }

#pragma unroll
  for (int i = 0; i < 4; ++i) {
    int R = blk * 128 + wr * 64 + i * 16 + (l >> 4) * 4;
#pragma unroll
    for (int j = 0; j < 4; ++j) {
      int o = wc * 64 + j * 16 + (l & 15);
      float bv = bias[o];
#pragma unroll
      for (int rr = 0; rr < 4; ++rr) {
        int Rr = R + rr;
        int n = Rr >> 5, b = Rr & 31;
        size_t base = ((size_t)b * NN + n) * 64;
        float val = 1.f / (1.f + expf(-(acc[i][j][rr] + bv)));
        if (o < 64)
          RHX[base + o] = val * hx[base + o];
        else
          UBUF[base + (o - 64)] = val;
      }
    }
  }
}

// ---------------------------------------------------------------------------
// K6: candidate Wout GEMM (plain fp16 MFMA; terminal op, no amplification)
// + fused tanh + gate -> out.
// ---------------------------------------------------------------------------
__global__ __launch_bounds__(256, 2) void k_wout_c_mfma(
    const _Float16* __restrict__ CAT2h, const _Float16* __restrict__ XP0,
    const _Float16* __restrict__ WTh, const float* __restrict__ bias,
    const float* __restrict__ UBUF, const float* __restrict__ hx,
    float* __restrict__ out) {
  constexpr int KTOT = 192, KC = 4, KT = 6;
  __shared__ _Float16 ldsAh[2][4096];
  __shared__ _Float16 ldsBh[2][2048];
  const int tid = threadIdx.x;
  const int blk = blockIdx.x;
  const int l = tid & 63;
  const int w = tid >> 6;

  const int t0 = tid, t1 = 256 + tid;
  const int r0 = t0 >> 2, q0 = (t0 & 3) ^ (r0 & 3);
  const int r1 = t1 >> 2, q1 = (t1 & 3) ^ (r1 & 3);
  const size_t R0 = (size_t)blk * 128 + r0, R1 = (size_t)blk * 128 + r1;
  const _Float16* pA0ch = CAT2h + R0 * 128 + q0 * 8;
  const _Float16* pA1ch = CAT2h + R1 * 128 + q1 * 8;
  const _Float16* pA0x = XP0 + R0 * 64 + q0 * 8;
  const _Float16* pA1x = XP0 + R1 * 64 + q1 * 8;
  const int rb = tid >> 2, qb = (tid & 3) ^ (rb & 3);
  const _Float16* pBh = WTh + (size_t)rb * KTOT + qb * 8;

  const int ps = ((l >> 4) ^ (l & 3)) * 8;
  int offA[2], offB[4];
#pragma unroll
  for (int i = 0; i < 2; ++i)
    offA[i] = (w * 32 + i * 16 + (l & 15)) * 32 + ps;
#pragma unroll
  for (int j = 0; j < 4; ++j) offB[j] = (j * 16 + (l & 15)) * 32 + ps;

  f32x4 acc[2][4];
#pragma unroll
  for (int i = 0; i < 2; ++i)
#pragma unroll
    for (int j = 0; j < 4; ++j) acc[i][j] = (f32x4){0.f, 0.f, 0.f, 0.f};

  load_lds16(pA0ch, &ldsAh[0][0] + t0 * 8);
  load_lds16(pA1ch, &ldsAh[0][0] + t1 * 8);
  load_lds16(pBh, &ldsBh[0][0] + tid * 8);

  int buf = 0;
  for (int kt = 0; kt < KT; ++kt) {
    __syncthreads();
    if (kt + 1 < KT) {
      int k1 = kt + 1;
      const _Float16* a0 =
          (k1 < KC) ? pA0ch + k1 * 32 : pA0x + (k1 - KC) * 32;
      const _Float16* a1 =
          (k1 < KC) ? pA1ch + k1 * 32 : pA1x + (k1 - KC) * 32;
      load_lds16(a0, &ldsAh[buf ^ 1][0] + t0 * 8);
      load_lds16(a1, &ldsAh[buf ^ 1][0] + t1 * 8);
      load_lds16(pBh + k1 * 32, &ldsBh[buf ^ 1][0] + tid * 8);
    }
    f16x8 ah[2], bh[4];
#pragma unroll
    for (int i = 0; i < 2; ++i) ah[i] = *(const f16x8*)(&ldsAh[buf][offA[i]]);
#pragma unroll
    for (int j = 0; j < 4; ++j) bh[j] = *(const f16x8*)(&ldsBh[buf][offB[j]]);
#pragma unroll
    for (int i = 0; i < 2; ++i)
#pragma unroll
      for (int j = 0; j < 4; ++j)
        acc[i][j] = __builtin_amdgcn_mfma_f32_16x16x32_f16(ah[i], bh[j],
                                                           acc[i][j], 0, 0, 0);
    buf ^= 1;
  }

#pragma unroll
  for (int i = 0; i < 2; ++i) {
    int R = blk * 128 + w * 32 + i * 16 + (l >> 4) * 4;
#pragma unroll
    for (int j = 0; j < 4; ++j) {
      int o = j * 16 + (l & 15);
      float bv = bias[o];
#pragma unroll
      for (int rr = 0; rr < 4; ++rr) {
        int Rr = R + rr;
        int n = Rr >> 5, b = Rr & 31;
        size_t idx = ((size_t)b * NN + n) * 64 + o;
        float cval = tanhf(acc[i][j][rr] + bv);
        float u = UBUF[idx];
        out[idx] = u * hx[idx] + (1.f - u) * cval;
      }
    }
  }
}

// ---------------------------------------------------------------------------
extern "C" void kernel_launch(void* const* d_in, const int* in_sizes, int n_in,
                              void* d_out, int out_size, void* d_ws,
                              size_t ws_size, hipStream_t stream) {
  const float* inputs   = (const float*)d_in[0];
  const float* hx       = (const float*)d_in[1];
  const float* adj      = (const float*)d_in[2];
  const float* mask     = (const float*)d_in[3];
  const float* W_ru     = (const float*)d_in[4];
  const float* Watt_ru  = (const float*)d_in[5];
  const float* Watt1_ru = (const float*)d_in[6];
  const float* Wout_ru  = (const float*)d_in[7];
  const float* b_ru     = (const float*)d_in[8];
  const float* W_c      = (const float*)d_in[9];
  const float* Watt_c   = (const float*)d_in[10];
  const float* Watt1_c  = (const float*)d_in[11];
  const float* Wout_c   = (const float*)d_in[12];
  const float* b_c      = (const float*)d_in[13];

  // workspace arena (~178.5 MB), same as round 6
  char* ws = (char*)d_ws;
  _Float16*  X0P   = (_Float16*)(ws);
  _Float16*  XPD   = (_Float16*)(ws + 6291456);
  _Float16*  XP0   = (_Float16*)(ws + 90177536);
  _Float16*  XP0T  = (_Float16*)(ws + 98566144);
  _Float16*  CAT2h = (_Float16*)(ws + 106954752);
  _Float16*  CAT2l = (_Float16*)(ws + 123731968);
  float*     RHX   = (float*)(ws + 140509184);
  float*     UBUF  = (float*)(ws + 148897792);
  _Float16*  A_all = (_Float16*)(ws + 157286400);
  _Float16*  WThru = (_Float16*)(ws + 178257920);
  _Float16*  WTlru = (_Float16*)(ws + 178356224);
  _Float16*  WThc  = (_Float16*)(ws + 178454528);
  _Float16*  WTlc  = (_Float16*)(ws + 178479104);
  float*     out   = (float*)d_out;

  k_build_amats<<<1024, 256, 0, stream>>>(adj, mask, A_all);
  k_prep_wout<<<240, 256, 0, stream>>>(Wout_ru, Wout_c, WThru, WTlru, WThc,
                                       WTlc);

  // ---- gate gconv (O = 2U = 128) ----
  k_build_x0p<<<dim3(32, 16), 256, 0, stream>>>(inputs, hx, X0P);
  k_proj0_mfma<128><<<256, 256, 0, stream>>>(X0P, W_ru, XP0, XP0T);
  k_supports2_mfma<4096><<<dim3(32, 80), 256, 0, stream>>>(A_all, XP0T, XPD);
  k_attend_mfma<128><<<1024, 256, 0, stream>>>((const __half*)XPD, Watt_ru,
                                               Watt1_ru, CAT2h, CAT2l);
  k_wout_ru_mfma<<<256, 256, 0, stream>>>(CAT2h, CAT2l, XP0, WThru, WTlru,
                                          b_ru, hx, RHX, UBUF);
  // ---- candidate gconv (O = U = 64), state = r*hx ----
  k_build_x0p<<<dim3(32, 16), 256, 0, stream>>>(inputs, RHX, X0P);
  k_proj0_mfma<64><<<128, 256, 0, stream>>>(X0P, W_c, XP0, XP0T);
  k_supports2_mfma<2048><<<dim3(16, 80), 256, 0, stream>>>(A_all, XP0T, XPD);
  k_attend_mfma<64><<<1024, 256, 0, stream>>>((const __half*)XPD, Watt_c,
                                              Watt1_c, CAT2h, CAT2l);
  k_wout_c_mfma<<<256, 256, 0, stream>>>(CAT2h, XP0, WThc, b_c,
                                         UBUF, hx, out);
}